// Round 3
// baseline (627.678 us; speedup 1.0000x reference)
//
#include <hip/hip_runtime.h>
#include <hip/hip_bf16.h>
#include <math.h>

// CFConv: out[a][f] = sum_n x[nbr[a][n]][f] * W[a][n][f]
//   W = (softplus(rbf @ w1 + b1)) @ w2 + b2
// N=20000 atoms, NB=32 neighbors, F=128, RBF=64.
//
// R3 = R2 with the bit_cast fixed (memcpy; __hip_bfloat162 is not trivially
// copyable on this ROCm). Structure: 512-thread blocks (8 waves), each wave
// owns ONE atom, processed as two sequential 16-row halves (mt).
// LDS = w1f(16K) + w2f(32K) + hbuf(32K) = exactly 80 KB -> 2 blocks/CU
// (16 waves/CU vs 8 in R1). W never touches LDS: epilogue consumes W in MFMA
// C-layout (per-lane x gathers + shfl_xor butterfly over row-quads).

#define NB     32
#define FD     128
#define RD     64
#define WAVES  8
#define NTILES 2500   // 20000 / 8

typedef short  short8  __attribute__((ext_vector_type(8)));
typedef float  floatx4 __attribute__((ext_vector_type(4)));

static __device__ __forceinline__ unsigned pk2(float a, float b) {
  // packed fp32->bf16 RNE (v_cvt_pk_bf16_f32 on gfx950); low 16 = a
  __hip_bfloat162 h = __float22bfloat162_rn(float2{a, b});
  unsigned u;
  __builtin_memcpy(&u, &h, sizeof(u));
  return u;
}

static __device__ __forceinline__ float softplus(float v) {
  // stable: max(v,0) + log(1 + exp(-|v|)); arg of exp <= 0 so no overflow.
  return fmaxf(v, 0.0f) + __logf(1.0f + __expf(-fabsf(v)));
}

__global__ __launch_bounds__(512, 4)  // 4 waves/EU = 2 blocks/CU; caps VGPR at 128
void cfconv_kernel(const float* __restrict__ x,
                   const float* __restrict__ rbf,
                   const int*   __restrict__ nbr,
                   const float* __restrict__ w1,
                   const float* __restrict__ b1,
                   const float* __restrict__ w2,
                   const float* __restrict__ b2,
                   float* __restrict__ out) {
  // B-fragment layout: frag[kt*8+nt][lane][j] = B[kt*32 + (lane>>4)*8 + j][nt*16 + (lane&15)]
  __shared__ __align__(16) short w1f[16][64][8];        // 16 KB
  __shared__ __align__(16) short w2f[32][64][8];        // 32 KB
  // H staging, 16 rows x 128 cols bf16 per wave; 16B-block XOR swizzle:
  // element (row, col) lives at hbuf[band+row][ ((col>>3 ^ row)&15)*8 + (col&7) ]
  __shared__ __align__(16) short hbuf[WAVES * 16][128]; // 32 KB -> total exactly 80 KB

  const int tid  = threadIdx.x;
  const int lane = tid & 63;
  const int wv   = tid >> 6;
  const int q    = lane >> 4;   // k-quad (A/B) or row-quad (C)
  const int ln   = lane & 15;   // m (A/C row) or n (B/C col) inside a 16-tile

  // ---- prepack weights: coalesced fp32 global reads -> bf16 B-frags in LDS ----
  for (int i = tid; i < RD * FD; i += 512) {
    int k = i >> 7, n = i & 127, kk = k & 31;
    w1f[(k >> 5) * 8 + (n >> 4)][(kk >> 3) * 16 + (n & 15)][kk & 7] = (short)pk2(w1[i], 0.f);
  }
  for (int i = tid; i < FD * FD; i += 512) {
    int k = i >> 7, n = i & 127, kk = k & 31;
    w2f[(k >> 5) * 8 + (n >> 4)][(kk >> 3) * 16 + (n & 15)][kk & 7] = (short)pk2(w2[i], 0.f);
  }
  float b1v[8], b2v[8];
#pragma unroll
  for (int nt = 0; nt < 8; ++nt) {
    b1v[nt] = b1[nt * 16 + ln];
    b2v[nt] = b2[nt * 16 + ln];
  }
  __syncthreads();  // the only barrier; hbuf use below is wave-private

  short (*band)[128] = &hbuf[wv * 16];

  for (int tile = blockIdx.x; tile < NTILES; tile += gridDim.x) {
    const int atom = tile * WAVES + wv;
    const int prow = atom * NB;

    // ---- rbf fp32 loads for both 16-row halves, then pack to bf16 A-frags ----
    floatx4 raw[2][2][2];
#pragma unroll
    for (int mt = 0; mt < 2; ++mt) {
      const float* src = rbf + (prow + mt * 16 + ln) * RD + q * 8;
#pragma unroll
      for (int kt = 0; kt < 2; ++kt) {
        raw[mt][kt][0] = *(const floatx4*)(src + kt * 32);
        raw[mt][kt][1] = *(const floatx4*)(src + kt * 32 + 4);
      }
    }
    short8 afrag[2][2];
#pragma unroll
    for (int mt = 0; mt < 2; ++mt)
#pragma unroll
      for (int kt = 0; kt < 2; ++kt) {
        union { short8 s8; unsigned u[4]; } f;
        f.u[0] = pk2(raw[mt][kt][0][0], raw[mt][kt][0][1]);
        f.u[1] = pk2(raw[mt][kt][0][2], raw[mt][kt][0][3]);
        f.u[2] = pk2(raw[mt][kt][1][0], raw[mt][kt][1][1]);
        f.u[3] = pk2(raw[mt][kt][1][2], raw[mt][kt][1][3]);
        afrag[mt][kt] = f.s8;
      }

    const int* nbp = nbr + prow;
    float psum[8];
#pragma unroll
    for (int nt = 0; nt < 8; ++nt) psum[nt] = 0.f;

#pragma unroll
    for (int mt = 0; mt < 2; ++mt) {
      // ---- GEMM1: H = softplus(rbf @ w1 + b1), 16 rows, K=64 ----
      floatx4 acc1[8];
#pragma unroll
      for (int nt = 0; nt < 8; ++nt) acc1[nt] = floatx4{0.f, 0.f, 0.f, 0.f};
#pragma unroll
      for (int kt = 0; kt < 2; ++kt)
#pragma unroll
        for (int nt = 0; nt < 8; ++nt) {
          short8 bfrag = *(const short8*)&w1f[kt * 8 + nt][lane][0];
          acc1[nt] = __builtin_amdgcn_mfma_f32_16x16x32_bf16(
              afrag[mt][kt], bfrag, acc1[nt], 0, 0, 0);
        }

      // ---- softplus -> bf16 -> swizzled LDS (C-layout: row q*4+r, col nt*16+ln) ----
#pragma unroll
      for (int nt = 0; nt < 8; ++nt) {
        const int c  = nt * 16 + ln;
        const int cb = c >> 3, cl = c & 7;
        float s0 = softplus(acc1[nt][0] + b1v[nt]);
        float s1 = softplus(acc1[nt][1] + b1v[nt]);
        float s2 = softplus(acc1[nt][2] + b1v[nt]);
        float s3 = softplus(acc1[nt][3] + b1v[nt]);
        unsigned u01 = pk2(s0, s1), u23 = pk2(s2, s3);
        band[q * 4 + 0][(((cb ^ (q * 4 + 0)) & 15) << 3) | cl] = (short)u01;
        band[q * 4 + 1][(((cb ^ (q * 4 + 1)) & 15) << 3) | cl] = (short)(u01 >> 16);
        band[q * 4 + 2][(((cb ^ (q * 4 + 2)) & 15) << 3) | cl] = (short)u23;
        band[q * 4 + 3][(((cb ^ (q * 4 + 3)) & 15) << 3) | cl] = (short)(u23 >> 16);
      }

      // ---- H A-frags back from LDS: row=ln, cols kt*32+q*8..+7 (b128, swizzled) ----
      short8 hfrag[4];
#pragma unroll
      for (int kt = 0; kt < 4; ++kt) {
        const int pb = ((kt * 4 + q) ^ ln) & 15;
        hfrag[kt] = *(const short8*)&band[ln][pb << 3];
      }

      // ---- GEMM2: W = H @ w2 (+b2 in epilogue), K=128 ----
      floatx4 acc2[8];
#pragma unroll
      for (int nt = 0; nt < 8; ++nt) acc2[nt] = floatx4{0.f, 0.f, 0.f, 0.f};
#pragma unroll
      for (int kt = 0; kt < 4; ++kt)
#pragma unroll
        for (int nt = 0; nt < 8; ++nt) {
          short8 bfrag = *(const short8*)&w2f[kt * 8 + nt][lane][0];
          acc2[nt] = __builtin_amdgcn_mfma_f32_16x16x32_bf16(
              hfrag[kt], bfrag, acc2[nt], 0, 0, 0);
        }

      // ---- epilogue in C-layout: lane owns rows q*4+r, cols nt*16+ln; W stays fp32 ----
#pragma unroll
      for (int r = 0; r < 4; ++r) {
        const int j = nbp[mt * 16 + q * 4 + r];   // 16 lanes share each index (L1 bcast)
        const float* xr = x + j * FD + ln;
#pragma unroll
        for (int nt = 0; nt < 8; ++nt)
          psum[nt] = fmaf(xr[nt * 16], acc2[nt][r] + b2v[nt], psum[nt]);
      }
    }

    // ---- reduce over the 4 row-quads (lane bits 4,5), then coalesced store ----
#pragma unroll
    for (int nt = 0; nt < 8; ++nt) {
      psum[nt] += __shfl_xor(psum[nt], 16);
      psum[nt] += __shfl_xor(psum[nt], 32);
    }
    float v0 = (q == 0) ? psum[0] : (q == 1) ? psum[2] : (q == 2) ? psum[4] : psum[6];
    float v1 = (q == 0) ? psum[1] : (q == 1) ? psum[3] : (q == 2) ? psum[5] : psum[7];
    out[atom * FD + q * 32 + ln]      = v0;
    out[atom * FD + q * 32 + 16 + ln] = v1;
  }
}

extern "C" void kernel_launch(void* const* d_in, const int* in_sizes, int n_in,
                              void* d_out, int out_size, void* d_ws, size_t ws_size,
                              hipStream_t stream) {
  const float* x   = (const float*)d_in[0];
  const float* rbf = (const float*)d_in[1];
  const int*   nbr = (const int*)d_in[2];
  const float* w1  = (const float*)d_in[3];
  const float* b1  = (const float*)d_in[4];
  const float* w2  = (const float*)d_in[5];
  const float* b2  = (const float*)d_in[6];
  float* out = (float*)d_out;

  // 80 KB LDS -> 2 blocks/CU. 500 blocks x 5 tiles each: exact, all co-resident.
  cfconv_kernel<<<dim3(500), dim3(512), 0, stream>>>(x, rbf, nbr, w1, b1, w2, b2, out);
}

// Round 5
// 305.623 us; speedup vs baseline: 2.0538x; 2.0538x over previous
//
#include <hip/hip_runtime.h>
#include <hip/hip_bf16.h>
#include <math.h>

// CFConv: out[a][f] = sum_n x[nbr[a][n]][f] * W[a][n][f]
//   W = (softplus(rbf @ w1 + b1)) @ w2 + b2
// N=20000 atoms, NB=32 neighbors, F=128, RBF=64.
//
// R5 = R4 + aliasing fixes. R4's epilogue read LDS through unsigned* while W
// was stored through short lvalues -> TBAA no-alias -> compiler reordered the
// reads around the writes (absmax 33.9). Fix: memcpy for the punned read +
// compiler memory barriers at every in-wave LDS write->read transition.
//
// Structure: 80 KB LDS (2 blocks/CU, 16 waves/CU). 512-thread blocks (8
// waves); each wave owns ONE atom as two sequential 16-row halves. Per half:
// GEMM1(K=64) -> softplus -> H(bf16) into wave-private swizzled LDS band ->
// GEMM2(K=128) -> W(bf16) into same band -> coalesced epilogue (512B x-row
// reads, lane owns f=2*lane,2*lane+1).

#define NB     32
#define FD     128
#define RD     64
#define WAVES  8
#define NTILES 2500   // 20000 / 8

typedef short  short8  __attribute__((ext_vector_type(8)));
typedef float  floatx4 __attribute__((ext_vector_type(4)));
typedef float  floatx2 __attribute__((ext_vector_type(2)));

#define LDS_FENCE() asm volatile("" ::: "memory")  // compiler-only ordering, no instr

static __device__ __forceinline__ unsigned pk2(float a, float b) {
  // packed fp32->bf16 RNE (v_cvt_pk_bf16_f32 on gfx950); low 16 = a
  __hip_bfloat162 h = __float22bfloat162_rn(float2{a, b});
  unsigned u;
  __builtin_memcpy(&u, &h, sizeof(u));
  return u;
}

static __device__ __forceinline__ float softplus(float v) {
  // stable: max(v,0) + log(1 + exp(-|v|)); arg of exp <= 0 so no overflow.
  return fmaxf(v, 0.0f) + __logf(1.0f + __expf(-fabsf(v)));
}

__global__ __launch_bounds__(512, 4)  // 4 waves/EU = 2 blocks/CU (<=128 regs/wave)
void cfconv_kernel(const float* __restrict__ x,
                   const float* __restrict__ rbf,
                   const int*   __restrict__ nbr,
                   const float* __restrict__ w1,
                   const float* __restrict__ b1,
                   const float* __restrict__ w2,
                   const float* __restrict__ b2,
                   float* __restrict__ out) {
  // B-fragment layout: frag[kt*8+nt][lane][j] = B[kt*32 + (lane>>4)*8 + j][nt*16 + (lane&15)]
  __shared__ __align__(16) short w1f[16][64][8];        // 16 KB
  __shared__ __align__(16) short w2f[32][64][8];        // 32 KB
  // per-wave 16-row x 128-col bf16 staging (H, then W); 16B-block XOR swizzle:
  // element (row, col) lives at band[row][ ((col>>3 ^ row)&15)*8 + (col&7) ]
  __shared__ __align__(16) short hbuf[WAVES * 16][128]; // 32 KB -> total exactly 80 KB

  const int tid  = threadIdx.x;
  const int lane = tid & 63;
  const int wv   = tid >> 6;
  const int q    = lane >> 4;   // k-quad (A/B) or row-quad (C)
  const int ln   = lane & 15;   // m (A/C row) or n (B/C col) inside a 16-tile

  // ---- prepack weights: coalesced fp32 global reads -> bf16 B-frags in LDS ----
  for (int i = tid; i < RD * FD; i += 512) {
    int k = i >> 7, n = i & 127, kk = k & 31;
    w1f[(k >> 5) * 8 + (n >> 4)][(kk >> 3) * 16 + (n & 15)][kk & 7] = (short)pk2(w1[i], 0.f);
  }
  for (int i = tid; i < FD * FD; i += 512) {
    int k = i >> 7, n = i & 127, kk = k & 31;
    w2f[(k >> 5) * 8 + (n >> 4)][(kk >> 3) * 16 + (n & 15)][kk & 7] = (short)pk2(w2[i], 0.f);
  }
  float b1v[8], b2v[8];
#pragma unroll
  for (int nt = 0; nt < 8; ++nt) {
    b1v[nt] = b1[nt * 16 + ln];
    b2v[nt] = b2[nt * 16 + ln];
  }
  __syncthreads();  // the only barrier; hbuf use below is wave-private

  short (*band)[128] = &hbuf[wv * 16];
  const int cb2 = (lane * 2) >> 3;   // epilogue col-block for f = {2*lane, 2*lane+1}
  const int cl2 = (lane * 2) & 7;

  for (int tile = blockIdx.x; tile < NTILES; tile += gridDim.x) {
    const int atom = tile * WAVES + wv;
    const int prow = atom * NB;
    const int* nbp = nbr + prow;

    float o0 = 0.f, o1 = 0.f;

#pragma unroll
    for (int mt = 0; mt < 2; ++mt) {
      // ---- rbf A-frags for this 16-row half (nontemporal: streamed once) ----
      const float* src = rbf + (prow + mt * 16 + ln) * RD + q * 8;
      short8 afrag[2];
#pragma unroll
      for (int kt = 0; kt < 2; ++kt) {
        floatx4 lo = __builtin_nontemporal_load((const floatx4*)(src + kt * 32));
        floatx4 hi = __builtin_nontemporal_load((const floatx4*)(src + kt * 32 + 4));
        union { short8 s8; unsigned u[4]; } f;
        f.u[0] = pk2(lo[0], lo[1]);
        f.u[1] = pk2(lo[2], lo[3]);
        f.u[2] = pk2(hi[0], hi[1]);
        f.u[3] = pk2(hi[2], hi[3]);
        afrag[kt] = f.s8;
      }

      // ---- GEMM1: H = softplus(rbf @ w1 + b1), 16 rows, K=64 ----
      floatx4 acc[8];
#pragma unroll
      for (int nt = 0; nt < 8; ++nt) acc[nt] = floatx4{0.f, 0.f, 0.f, 0.f};
#pragma unroll
      for (int kt = 0; kt < 2; ++kt)
#pragma unroll
        for (int nt = 0; nt < 8; ++nt) {
          short8 bfrag = *(const short8*)&w1f[kt * 8 + nt][lane][0];
          acc[nt] = __builtin_amdgcn_mfma_f32_16x16x32_bf16(
              afrag[kt], bfrag, acc[nt], 0, 0, 0);
        }

      // ---- softplus -> bf16 -> swizzled band (C-layout: row q*4+r, col nt*16+ln) ----
#pragma unroll
      for (int nt = 0; nt < 8; ++nt) {
        const int c  = nt * 16 + ln;
        const int cb = c >> 3, cl = c & 7;
        unsigned u01 = pk2(softplus(acc[nt][0] + b1v[nt]), softplus(acc[nt][1] + b1v[nt]));
        unsigned u23 = pk2(softplus(acc[nt][2] + b1v[nt]), softplus(acc[nt][3] + b1v[nt]));
        band[q * 4 + 0][(((cb ^ (q * 4 + 0)) & 15) << 3) | cl] = (short)u01;
        band[q * 4 + 1][(((cb ^ (q * 4 + 1)) & 15) << 3) | cl] = (short)(u01 >> 16);
        band[q * 4 + 2][(((cb ^ (q * 4 + 2)) & 15) << 3) | cl] = (short)u23;
        band[q * 4 + 3][(((cb ^ (q * 4 + 3)) & 15) << 3) | cl] = (short)(u23 >> 16);
      }
      LDS_FENCE();  // H writes must precede hfrag reads in program order

      // ---- H A-frags from band: row=ln, cols kt*32+q*8..+7 (b128, swizzled) ----
      short8 hfrag[4];
#pragma unroll
      for (int kt = 0; kt < 4; ++kt) {
        const int pb = ((kt * 4 + q) ^ ln) & 15;
        hfrag[kt] = *(const short8*)&band[ln][pb << 3];
      }
      LDS_FENCE();  // hfrag reads must precede W overwrite

      // ---- GEMM2: W = H @ w2 + b2, K=128 (reuse acc) ----
#pragma unroll
      for (int nt = 0; nt < 8; ++nt) acc[nt] = floatx4{0.f, 0.f, 0.f, 0.f};
#pragma unroll
      for (int kt = 0; kt < 4; ++kt)
#pragma unroll
        for (int nt = 0; nt < 8; ++nt) {
          short8 bfrag = *(const short8*)&w2f[kt * 8 + nt][lane][0];
          acc[nt] = __builtin_amdgcn_mfma_f32_16x16x32_bf16(
              hfrag[kt], bfrag, acc[nt], 0, 0, 0);
        }

      // ---- W (bf16) back into the same band ----
#pragma unroll
      for (int nt = 0; nt < 8; ++nt) {
        const int c  = nt * 16 + ln;
        const int cb = c >> 3, cl = c & 7;
        unsigned u01 = pk2(acc[nt][0] + b2v[nt], acc[nt][1] + b2v[nt]);
        unsigned u23 = pk2(acc[nt][2] + b2v[nt], acc[nt][3] + b2v[nt]);
        band[q * 4 + 0][(((cb ^ (q * 4 + 0)) & 15) << 3) | cl] = (short)u01;
        band[q * 4 + 1][(((cb ^ (q * 4 + 1)) & 15) << 3) | cl] = (short)(u01 >> 16);
        band[q * 4 + 2][(((cb ^ (q * 4 + 2)) & 15) << 3) | cl] = (short)u23;
        band[q * 4 + 3][(((cb ^ (q * 4 + 3)) & 15) << 3) | cl] = (short)(u23 >> 16);
      }
      LDS_FENCE();  // W writes must precede epilogue reads

      // ---- epilogue: 16 rows, coalesced 512B x-row reads; lane owns f=2*lane,+1 ----
#pragma unroll 4
      for (int r = 0; r < 16; ++r) {
        const int j = nbp[mt * 16 + r];   // wave-uniform -> s_load
        floatx2 xv = *(const floatx2*)(x + j * FD + lane * 2);
        unsigned pw;
        __builtin_memcpy(&pw, &band[r][(((cb2 ^ r) & 15) << 3) | cl2], 4);  // may-alias read
        o0 = fmaf(xv[0], __builtin_bit_cast(float, pw << 16), o0);
        o1 = fmaf(xv[1], __builtin_bit_cast(float, pw & 0xFFFF0000u), o1);
      }
      LDS_FENCE();  // epilogue reads must precede next half's H writes
    }

    __builtin_nontemporal_store(floatx2{o0, o1}, (floatx2*)(out + atom * FD + lane * 2));
  }
}

extern "C" void kernel_launch(void* const* d_in, const int* in_sizes, int n_in,
                              void* d_out, int out_size, void* d_ws, size_t ws_size,
                              hipStream_t stream) {
  const float* x   = (const float*)d_in[0];
  const float* rbf = (const float*)d_in[1];
  const int*   nbr = (const int*)d_in[2];
  const float* w1  = (const float*)d_in[3];
  const float* b1  = (const float*)d_in[4];
  const float* w2  = (const float*)d_in[5];
  const float* b2  = (const float*)d_in[6];
  float* out = (float*)d_out;

  // 80 KB LDS -> 2 blocks/CU. 500 blocks x 5 tiles each: exact, all co-resident.
  cfconv_kernel<<<dim3(500), dim3(512), 0, stream>>>(x, rbf, nbr, w1, b1, w2, b2, out);
}